// Round 5
// baseline (92.380 us; speedup 1.0000x reference)
//
#include <hip/hip_runtime.h>
#include <hip/hip_bf16.h>
#include <math.h>

#define C 128
#define RANK 64
#define NB 8192
#define BATCH 2
#define NCHUNK 128                 // 64-row chunks per batch
#define NBLK 256                   // persistent blocks (1 per CU)

typedef float f32x4 __attribute__((ext_vector_type(4)));
typedef short bf16x8 __attribute__((ext_vector_type(8)));
typedef unsigned short u16x4 __attribute__((ext_vector_type(4)));

__device__ __forceinline__ unsigned short f2b(float f) {
  __hip_bfloat16 h = __float2bfloat16(f);
  return *reinterpret_cast<unsigned short*>(&h);
}
__device__ __forceinline__ float b2f(unsigned short h) {
  union { unsigned u; float f; } v; v.u = ((unsigned)h) << 16;
  return v.f;
}
// cubic-tanh GELU, branch-free, |err| <= ~1e-3 vs exact erf form
__device__ __forceinline__ float gelu_fast(float y) {
  float u = y * (1.0f + 0.044715f * y * y);
  float e = __expf(1.5957691216057308f * u);
  float t = 1.0f - 2.0f / (e + 1.0f);
  return 0.5f * y * (1.0f + t);
}
#define MFMA(a, b, c) __builtin_amdgcn_mfma_f32_16x16x32_bf16(a, b, c, 0, 0, 0)

// Grid barrier: counter zeroed by hipMemsetAsync before launch; all NBLK
// blocks are co-resident (1 block/CU). Agent-scope release/acquire handles
// cross-XCD L2 non-coherence.
__device__ __forceinline__ void gbar(unsigned* bar, unsigned target) {
  __syncthreads();
  if (threadIdx.x == 0) {
    __threadfence();
    __hip_atomic_fetch_add(bar, 1u, __ATOMIC_RELEASE, __HIP_MEMORY_SCOPE_AGENT);
    while (__hip_atomic_load(bar, __ATOMIC_ACQUIRE, __HIP_MEMORY_SCOPE_AGENT) <
           target)
      __builtin_amdgcn_s_sleep(2);
  }
  __syncthreads();
}

// ---------------------------------------------------------------------------
// Fused persistent kernel, 256 blocks x 512 threads.
// P1: Gram partial (64 rows/block, MFMA) + colsum; blocks 0-5 also pack
//     W_w/phi_w into bf16 fragment order.           -> barrier(256)
// P2a: reduce partG -> gsumG (block-distributed); blocks 0-1 reduce partS.
//                                                   -> barrier(512)
// P2b: integral (r,32-col slab per block) -> itf fragment-order bf16.
//                                                   -> barrier(768)
// P3: rows [64e,64e+64): T1 phi=x*phi_w+phi_b; T2 acc=x*W_w+W_b;
//     T3 acc+=phi*integ; out=gelu_fast(acc). x re-read is same-CU L2-hot.
// Fragment order: o = ((nt*KT+kt)*64 + lane)*8 + j holds
//   B[k = kt*32 + (lane>>4)*8 + j][n = nt*16 + (lane&15)].
// ---------------------------------------------------------------------------
__global__ __launch_bounds__(512, 1) void k_fused(
    const float* __restrict__ x, const float* __restrict__ W_w,
    const float* __restrict__ W_b, const float* __restrict__ phi_w,
    const float* __restrict__ phi_b, const float* __restrict__ psi_w,
    const float* __restrict__ psi_b, float* __restrict__ out,
    unsigned short* __restrict__ partG, float* __restrict__ partS,
    float* __restrict__ gsumG, float* __restrict__ gsumS,
    unsigned short* __restrict__ wtf, unsigned short* __restrict__ pwf,
    unsigned short* __restrict__ itf, unsigned* __restrict__ bar) {
  __shared__ short xsT[C * 76];
  __shared__ float csp[4][C];
  __shared__ f32x4 red[512];
  __shared__ float psred[4][C];
  __shared__ float red2[2][16][32];
  __shared__ short phT[64 * 72];

  const int e = blockIdx.x;
  const int tid = threadIdx.x;
  const int l = tid & 63, w = tid >> 6;
  const int lr = l & 15, lq = l >> 4;

  // ================= Phase 1: Gram partial =================
  {
    const int b = e >> 7, chunk = e & 127;
    const float* xb = x + ((size_t)(b * NB + chunk * 64)) * C;
    const int c = tid & 127, ng = tid >> 7;
    float cs = 0.f;
#pragma unroll
    for (int it = 0; it < 4; ++it) {
      int n0 = it * 16 + ng * 4;
      u16x4 pv;
#pragma unroll
      for (int q = 0; q < 4; ++q) {
        float v = xb[(size_t)(n0 + q) * C + c];
        cs += v;
        pv[q] = f2b(v);
      }
      *(u16x4*)(&xsT[c * 76 + n0]) = pv;
    }
    csp[ng][c] = cs;
    __syncthreads();
    f32x4 acc[8];
#pragma unroll
    for (int tj = 0; tj < 8; ++tj) acc[tj] = (f32x4)(0.f);
    bf16x8 af[2];
#pragma unroll
    for (int kk = 0; kk < 2; ++kk)
      af[kk] = *(const bf16x8*)(&xsT[(w * 16 + lr) * 76 + kk * 32 + lq * 8]);
#pragma unroll
    for (int tj = 0; tj < 8; ++tj)
#pragma unroll
      for (int kk = 0; kk < 2; ++kk) {
        bf16x8 bfr = *(const bf16x8*)(&xsT[(tj * 16 + lr) * 76 + kk * 32 + lq * 8]);
        acc[tj] = MFMA(af[kk], bfr, acc[tj]);
      }
    unsigned short* dst = partG + (size_t)e * (C * C);
#pragma unroll
    for (int tj = 0; tj < 8; ++tj)
#pragma unroll
      for (int q = 0; q < 4; ++q) {
        int ci = w * 16 + lq * 4 + q;
        int cj = tj * 16 + lr;
        dst[ci * C + cj] = f2b(acc[tj][q]);
      }
    if (tid < C)
      partS[e * C + tid] = csp[0][tid] + csp[1][tid] + csp[2][tid] + csp[3][tid];
    // packing: blocks 0-3 -> wtf (4096 each), blocks 4-5 -> pwf (4096 each)
    if (e < 4) {
      int o0 = e * 4096 + tid * 8;
#pragma unroll
      for (int h = 0; h < 2; ++h) {
        u16x4 v;
#pragma unroll
        for (int q = 0; q < 4; ++q) {
          int o = o0 + h * 4 + q;
          int j = o & 7, lane = (o >> 3) & 63, kt = (o >> 9) & 3, nt = o >> 11;
          int n = nt * 16 + (lane & 15);
          int k = kt * 32 + ((lane >> 4) << 3) + j;
          v[q] = f2b(W_w[k * C + n]);
        }
        *(u16x4*)(wtf + o0 + h * 4) = v;
      }
    } else if (e < 6) {
      int o0 = (e - 4) * 4096 + tid * 8;
#pragma unroll
      for (int h = 0; h < 2; ++h) {
        u16x4 v;
#pragma unroll
        for (int q = 0; q < 4; ++q) {
          int o = o0 + h * 4 + q;
          int j = o & 7, lane = (o >> 3) & 63, kt = (o >> 9) & 3, nt = o >> 11;
          int r = nt * 16 + (lane & 15);
          int c2 = kt * 32 + ((lane >> 4) << 3) + j;
          v[q] = f2b(phi_w[c2 * RANK + r]);
        }
        *(u16x4*)(pwf + o0 + h * 4) = v;
      }
    }
  }
  gbar(bar, NBLK);

  // ================= Phase 2a: reduce partials =================
  {
    const int b = e >> 7, i0 = (e & 127) * 128;
    const int chg = tid >> 5, ig = tid & 31;   // 16 groups x 8 chunks
    f32x4 a = (f32x4)(0.f);
    const unsigned short* base =
        partG + (size_t)(b * NCHUNK + chg * 8) * (C * C) + i0 + ig * 4;
#pragma unroll
    for (int cc = 0; cc < 8; ++cc) {
      u16x4 v = *(const u16x4*)(base + (size_t)cc * (C * C));
#pragma unroll
      for (int q = 0; q < 4; ++q) a[q] += b2f(v[q]);
    }
    red[tid] = a;
    if (e < 2) {  // partS reduce for batch e
      const int grp = tid >> 7, cloc = tid & 127;
      float s = 0.f;
#pragma unroll
      for (int cc = 0; cc < 32; ++cc)
        s += partS[(size_t)(e * NCHUNK + grp * 32 + cc) * C + cloc];
      psred[grp][cloc] = s;
    }
    __syncthreads();
    if (tid < 32) {
      f32x4 s = red[tid];
#pragma unroll
      for (int g = 1; g < 16; ++g) {
        f32x4 r = red[g * 32 + tid];
#pragma unroll
        for (int q = 0; q < 4; ++q) s[q] += r[q];
      }
      *(f32x4*)(&gsumG[b * (C * C) + i0 + tid * 4]) = s;
    }
    if (e < 2 && tid < C)
      gsumS[e * C + tid] =
          psred[0][tid] + psred[1][tid] + psred[2][tid] + psred[3][tid];
  }
  gbar(bar, 2 * NBLK);

  // ================= Phase 2b: integral -> itf =================
  {
    const int r = e >> 2, chq = e & 3;
    const int kg = tid >> 5, c32 = tid & 31;   // 16 groups x 8 k's
    const int c = chq * 32 + c32;
    const float* psW = psi_w + (size_t)r * C + c;
    const float* G0 = gsumG + c;
    const float* G1 = gsumG + C * C + c;
    float a0 = 0.f, a1 = 0.f;
#pragma unroll
    for (int i = 0; i < 8; ++i) {
      int k = kg * 8 + i;
      float pw = psW[(size_t)k * (RANK * C)];
      a0 += pw * G0[k * C];
      a1 += pw * G1[k * C];
    }
    red2[0][kg][c32] = a0;
    red2[1][kg][c32] = a1;
    __syncthreads();
    if (tid < 64) {
      int b = tid >> 5, cc = tid & 31;
      float s = 0.f;
#pragma unroll
      for (int g = 0; g < 16; ++g) s += red2[b][g][cc];
      int cg = chq * 32 + cc;
      s += psi_b[r * C + cg] * gsumS[b * C + cg];
      s *= (1.0f / NB);
      int nt = cg >> 4, kt = r >> 5;
      int lane = ((r >> 3) & 3) * 16 + (cg & 15), j = r & 7;
      itf[(size_t)(((b * 8 + nt) * 2 + kt) * 64 + lane) * 8 + j] = f2b(s);
    }
  }
  gbar(bar, 3 * NBLK);

  // ================= Phase 3: fused main =================
  {
    const int wm = w >> 2, wn = w & 3;
    const int rows0 = e * 64;
    const int b = e >> 7;
    bf16x8 wb[2][4], pw4[4], itb[2][2];
    const bf16x8* WF = (const bf16x8*)wtf;
    const bf16x8* PF = (const bf16x8*)pwf;
    const bf16x8* IF = (const bf16x8*)itf;
#pragma unroll
    for (int j = 0; j < 2; ++j)
#pragma unroll
      for (int kt = 0; kt < 4; ++kt)
        wb[j][kt] = WF[((wn * 2 + j) * 4 + kt) * 64 + l];
#pragma unroll
    for (int kt = 0; kt < 4; ++kt) pw4[kt] = PF[(wn * 4 + kt) * 64 + l];
#pragma unroll
    for (int j = 0; j < 2; ++j)
#pragma unroll
      for (int kt = 0; kt < 2; ++kt)
        itb[j][kt] = IF[((b * 8 + wn * 2 + j) * 2 + kt) * 64 + l];
    // A-fragments from global x (L2-hot: same rows as phase 1)
    bf16x8 afr[2][4];
#pragma unroll
    for (int h = 0; h < 2; ++h) {
      const float* xr = x + (size_t)(rows0 + wm * 32 + h * 16 + lr) * C + lq * 8;
#pragma unroll
      for (int kt = 0; kt < 4; ++kt) {
        f32x4 v0 = *(const f32x4*)(xr + kt * 32);
        f32x4 v1 = *(const f32x4*)(xr + kt * 32 + 4);
        bf16x8 pv;
#pragma unroll
        for (int q = 0; q < 4; ++q) {
          pv[q] = (short)f2b(v0[q]);
          pv[q + 4] = (short)f2b(v1[q]);
        }
        afr[h][kt] = pv;
      }
    }
    float wbias0 = W_b[wn * 32 + lr], wbias1 = W_b[wn * 32 + 16 + lr];
    float pbias = phi_b[wn * 16 + lr];
    f32x4 acc[2][2], pacc[2];
#pragma unroll
    for (int i = 0; i < 2; ++i) {
      acc[i][0] = (f32x4)(wbias0);
      acc[i][1] = (f32x4)(wbias1);
      pacc[i] = (f32x4)(pbias);
    }
#pragma unroll
    for (int kt = 0; kt < 4; ++kt) {
      pacc[0] = MFMA(afr[0][kt], pw4[kt], pacc[0]);
      pacc[1] = MFMA(afr[1][kt], pw4[kt], pacc[1]);
      acc[0][0] = MFMA(afr[0][kt], wb[0][kt], acc[0][0]);
      acc[0][1] = MFMA(afr[0][kt], wb[1][kt], acc[0][1]);
      acc[1][0] = MFMA(afr[1][kt], wb[0][kt], acc[1][0]);
      acc[1][1] = MFMA(afr[1][kt], wb[1][kt], acc[1][1]);
    }
#pragma unroll
    for (int i = 0; i < 2; ++i)
#pragma unroll
      for (int q = 0; q < 4; ++q) {
        int row = wm * 32 + i * 16 + lq * 4 + q;
        phT[row * 72 + wn * 16 + lr] = (short)f2b(pacc[i][q]);
      }
    __syncthreads();
#pragma unroll
    for (int kt = 0; kt < 2; ++kt) {
      bf16x8 p0 = *(const bf16x8*)(&phT[(wm * 32 + lr) * 72 + kt * 32 + lq * 8]);
      bf16x8 p1 =
          *(const bf16x8*)(&phT[(wm * 32 + 16 + lr) * 72 + kt * 32 + lq * 8]);
      acc[0][0] = MFMA(p0, itb[0][kt], acc[0][0]);
      acc[0][1] = MFMA(p0, itb[1][kt], acc[0][1]);
      acc[1][0] = MFMA(p1, itb[0][kt], acc[1][0]);
      acc[1][1] = MFMA(p1, itb[1][kt], acc[1][1]);
    }
#pragma unroll
    for (int i = 0; i < 2; ++i)
#pragma unroll
      for (int j = 0; j < 2; ++j)
#pragma unroll
        for (int q = 0; q < 4; ++q) {
          int row = rows0 + wm * 32 + i * 16 + lq * 4 + q;
          int col = wn * 32 + j * 16 + lr;
          out[(size_t)row * C + col] = gelu_fast(acc[i][j][q]);
        }
  }
}

extern "C" void kernel_launch(void* const* d_in, const int* in_sizes, int n_in,
                              void* d_out, int out_size, void* d_ws, size_t ws_size,
                              hipStream_t stream) {
  const float* x     = (const float*)d_in[0];
  const float* W_w   = (const float*)d_in[1];
  const float* W_b   = (const float*)d_in[2];
  const float* phi_w = (const float*)d_in[3];
  const float* phi_b = (const float*)d_in[4];
  const float* psi_w = (const float*)d_in[5];
  const float* psi_b = (const float*)d_in[6];
  float* out = (float*)d_out;

  // ws: partG[256*16384 bf16] | partS[256*128 f32] | gsumG[2*16384 f32]
  //     | gsumS[256 f32] | wtf[16384 bf16] | pwf[8192 bf16] | itf[16384 bf16]
  //     | bar[1 u32]
  unsigned short* partG = (unsigned short*)d_ws;
  float* partS = (float*)(partG + (size_t)BATCH * NCHUNK * C * C);
  float* gsumG = partS + (size_t)BATCH * NCHUNK * C;
  float* gsumS = gsumG + BATCH * C * C;
  unsigned short* wtf = (unsigned short*)(gsumS + BATCH * C);
  unsigned short* pwf = wtf + 16384;
  unsigned short* itf = pwf + 8192;
  unsigned* bar = (unsigned*)(itf + 16384);

  hipMemsetAsync(bar, 0, sizeof(unsigned), stream);
  k_fused<<<NBLK, 512, 0, stream>>>(x, W_w, W_b, phi_w, phi_b, psi_w, psi_b,
                                    out, partG, partS, gsumG, gsumS, wtf, pwf,
                                    itf, bar);
}

// Round 6
// 82.735 us; speedup vs baseline: 1.1166x; 1.1166x over previous
//
#include <hip/hip_runtime.h>
#include <hip/hip_bf16.h>
#include <math.h>

#define C 128
#define RANK 64
#define NB 8192
#define BATCH 2
#define NCHUNK 128                 // 64-row chunks per batch
#define NBLK 256                   // persistent blocks (1 per CU)

typedef float f32x4 __attribute__((ext_vector_type(4)));
typedef short bf16x8 __attribute__((ext_vector_type(8)));
typedef unsigned short u16x4 __attribute__((ext_vector_type(4)));

__device__ __forceinline__ unsigned short f2b(float f) {
  __hip_bfloat16 h = __float2bfloat16(f);
  return *reinterpret_cast<unsigned short*>(&h);
}
__device__ __forceinline__ float b2f(unsigned short h) {
  union { unsigned u; float f; } v; v.u = ((unsigned)h) << 16;
  return v.f;
}
// cubic-tanh GELU, branch-free, |err| <= ~1e-3 vs exact erf form
__device__ __forceinline__ float gelu_fast(float y) {
  float u = y * (1.0f + 0.044715f * y * y);
  float e = __expf(1.5957691216057308f * u);
  float t = 1.0f - 2.0f / (e + 1.0f);
  return 0.5f * y * (1.0f + t);
}
#define MFMA(a, b, c) __builtin_amdgcn_mfma_f32_16x16x32_bf16(a, b, c, 0, 0, 0)

// Grid barrier, invalidation-storm-free: release fence + RELAXED add,
// RELAXED polling (no per-iteration buffer_inv), one acquire fence on exit.
__device__ __forceinline__ void gbar(unsigned* bar, unsigned target) {
  __syncthreads();
  if (threadIdx.x == 0) {
    __threadfence();   // release: write back this XCD's L2
    __hip_atomic_fetch_add(bar, 1u, __ATOMIC_RELAXED, __HIP_MEMORY_SCOPE_AGENT);
    while (__hip_atomic_load(bar, __ATOMIC_RELAXED, __HIP_MEMORY_SCOPE_AGENT) <
           target)
      __builtin_amdgcn_s_sleep(8);
    __threadfence();   // acquire: invalidate L1/L2 once before reading peers' data
  }
  __syncthreads();
}

// ---------------------------------------------------------------------------
// Fused persistent kernel, 256 blocks x 512 threads.
// P1: Gram partial (64 rows/block, MFMA) + colsum; blocks 0-5 also pack
//     W_w/phi_w into bf16 fragment order.           -> barrier(256)
// P2a: reduce partG -> gsumG (block-distributed); blocks 0-1 reduce partS.
//                                                   -> barrier(512)
// P2b: integral (r,32-col slab per block) -> itf fragment-order bf16.
//                                                   -> barrier(768)
// P3: rows [64e,64e+64): T1 phi=x*phi_w+phi_b; T2 acc=x*W_w+W_b;
//     T3 acc+=phi*integ; out=gelu_fast(acc). x re-read is same-CU L2-hot.
// Fragment order: o = ((nt*KT+kt)*64 + lane)*8 + j holds
//   B[k = kt*32 + (lane>>4)*8 + j][n = nt*16 + (lane&15)].
// ---------------------------------------------------------------------------
__global__ __launch_bounds__(512, 1) void k_fused(
    const float* __restrict__ x, const float* __restrict__ W_w,
    const float* __restrict__ W_b, const float* __restrict__ phi_w,
    const float* __restrict__ phi_b, const float* __restrict__ psi_w,
    const float* __restrict__ psi_b, float* __restrict__ out,
    unsigned short* __restrict__ partG, float* __restrict__ partS,
    float* __restrict__ gsumG, float* __restrict__ gsumS,
    unsigned short* __restrict__ wtf, unsigned short* __restrict__ pwf,
    unsigned short* __restrict__ itf, unsigned* __restrict__ bar) {
  __shared__ short xsT[C * 76];
  __shared__ float csp[4][C];
  __shared__ f32x4 red[512];
  __shared__ float psred[4][C];
  __shared__ float red2[2][16][32];
  __shared__ short phT[64 * 72];

  const int e = blockIdx.x;
  const int tid = threadIdx.x;
  const int l = tid & 63, w = tid >> 6;
  const int lr = l & 15, lq = l >> 4;

  // ================= Phase 1: Gram partial =================
  {
    const int b = e >> 7, chunk = e & 127;
    const float* xb = x + ((size_t)(b * NB + chunk * 64)) * C;
    const int c = tid & 127, ng = tid >> 7;
    float cs = 0.f;
#pragma unroll
    for (int it = 0; it < 4; ++it) {
      int n0 = it * 16 + ng * 4;
      u16x4 pv;
#pragma unroll
      for (int q = 0; q < 4; ++q) {
        float v = xb[(size_t)(n0 + q) * C + c];
        cs += v;
        pv[q] = f2b(v);
      }
      *(u16x4*)(&xsT[c * 76 + n0]) = pv;
    }
    csp[ng][c] = cs;
    __syncthreads();
    f32x4 acc[8];
#pragma unroll
    for (int tj = 0; tj < 8; ++tj) acc[tj] = (f32x4)(0.f);
    bf16x8 af[2];
#pragma unroll
    for (int kk = 0; kk < 2; ++kk)
      af[kk] = *(const bf16x8*)(&xsT[(w * 16 + lr) * 76 + kk * 32 + lq * 8]);
#pragma unroll
    for (int tj = 0; tj < 8; ++tj)
#pragma unroll
      for (int kk = 0; kk < 2; ++kk) {
        bf16x8 bfr = *(const bf16x8*)(&xsT[(tj * 16 + lr) * 76 + kk * 32 + lq * 8]);
        acc[tj] = MFMA(af[kk], bfr, acc[tj]);
      }
    unsigned short* dst = partG + (size_t)e * (C * C);
#pragma unroll
    for (int tj = 0; tj < 8; ++tj)
#pragma unroll
      for (int q = 0; q < 4; ++q) {
        int ci = w * 16 + lq * 4 + q;
        int cj = tj * 16 + lr;
        dst[ci * C + cj] = f2b(acc[tj][q]);
      }
    if (tid < C)
      partS[e * C + tid] = csp[0][tid] + csp[1][tid] + csp[2][tid] + csp[3][tid];
    // packing: blocks 0-3 -> wtf (4096 each), blocks 4-5 -> pwf (4096 each)
    if (e < 4) {
      int o0 = e * 4096 + tid * 8;
#pragma unroll
      for (int h = 0; h < 2; ++h) {
        u16x4 v;
#pragma unroll
        for (int q = 0; q < 4; ++q) {
          int o = o0 + h * 4 + q;
          int j = o & 7, lane = (o >> 3) & 63, kt = (o >> 9) & 3, nt = o >> 11;
          int n = nt * 16 + (lane & 15);
          int k = kt * 32 + ((lane >> 4) << 3) + j;
          v[q] = f2b(W_w[k * C + n]);
        }
        *(u16x4*)(wtf + o0 + h * 4) = v;
      }
    } else if (e < 6) {
      int o0 = (e - 4) * 4096 + tid * 8;
#pragma unroll
      for (int h = 0; h < 2; ++h) {
        u16x4 v;
#pragma unroll
        for (int q = 0; q < 4; ++q) {
          int o = o0 + h * 4 + q;
          int j = o & 7, lane = (o >> 3) & 63, kt = (o >> 9) & 3, nt = o >> 11;
          int r = nt * 16 + (lane & 15);
          int c2 = kt * 32 + ((lane >> 4) << 3) + j;
          v[q] = f2b(phi_w[c2 * RANK + r]);
        }
        *(u16x4*)(pwf + o0 + h * 4) = v;
      }
    }
  }
  gbar(bar, NBLK);

  // ================= Phase 2a: reduce partials =================
  {
    const int b = e >> 7, i0 = (e & 127) * 128;
    const int chg = tid >> 5, ig = tid & 31;   // 16 groups x 8 chunks
    f32x4 a = (f32x4)(0.f);
    const unsigned short* base =
        partG + (size_t)(b * NCHUNK + chg * 8) * (C * C) + i0 + ig * 4;
#pragma unroll
    for (int cc = 0; cc < 8; ++cc) {
      u16x4 v = *(const u16x4*)(base + (size_t)cc * (C * C));
#pragma unroll
      for (int q = 0; q < 4; ++q) a[q] += b2f(v[q]);
    }
    red[tid] = a;
    if (e < 2) {  // partS reduce for batch e
      const int grp = tid >> 7, cloc = tid & 127;
      float s = 0.f;
#pragma unroll
      for (int cc = 0; cc < 32; ++cc)
        s += partS[(size_t)(e * NCHUNK + grp * 32 + cc) * C + cloc];
      psred[grp][cloc] = s;
    }
    __syncthreads();
    if (tid < 32) {
      f32x4 s = red[tid];
#pragma unroll
      for (int g = 1; g < 16; ++g) {
        f32x4 r = red[g * 32 + tid];
#pragma unroll
        for (int q = 0; q < 4; ++q) s[q] += r[q];
      }
      *(f32x4*)(&gsumG[b * (C * C) + i0 + tid * 4]) = s;
    }
    if (e < 2 && tid < C)
      gsumS[e * C + tid] =
          psred[0][tid] + psred[1][tid] + psred[2][tid] + psred[3][tid];
  }
  gbar(bar, 2 * NBLK);

  // ================= Phase 2b: integral -> itf =================
  {
    const int r = e >> 2, chq = e & 3;
    const int kg = tid >> 5, c32 = tid & 31;   // 16 groups x 8 k's
    const int c = chq * 32 + c32;
    const float* psW = psi_w + (size_t)r * C + c;
    const float* G0 = gsumG + c;
    const float* G1 = gsumG + C * C + c;
    float a0 = 0.f, a1 = 0.f;
#pragma unroll
    for (int i = 0; i < 8; ++i) {
      int k = kg * 8 + i;
      float pw = psW[(size_t)k * (RANK * C)];
      a0 += pw * G0[k * C];
      a1 += pw * G1[k * C];
    }
    red2[0][kg][c32] = a0;
    red2[1][kg][c32] = a1;
    __syncthreads();
    if (tid < 64) {
      int b = tid >> 5, cc = tid & 31;
      float s = 0.f;
#pragma unroll
      for (int g = 0; g < 16; ++g) s += red2[b][g][cc];
      int cg = chq * 32 + cc;
      s += psi_b[r * C + cg] * gsumS[b * C + cg];
      s *= (1.0f / NB);
      int nt = cg >> 4, kt = r >> 5;
      int lane = ((r >> 3) & 3) * 16 + (cg & 15), j = r & 7;
      itf[(size_t)(((b * 8 + nt) * 2 + kt) * 64 + lane) * 8 + j] = f2b(s);
    }
  }
  gbar(bar, 3 * NBLK);

  // ================= Phase 3: fused main =================
  {
    const int wm = w >> 2, wn = w & 3;
    const int rows0 = e * 64;
    const int b = e >> 7;
    bf16x8 wb[2][4], pw4[4], itb[2][2];
    const bf16x8* WF = (const bf16x8*)wtf;
    const bf16x8* PF = (const bf16x8*)pwf;
    const bf16x8* IF = (const bf16x8*)itf;
#pragma unroll
    for (int j = 0; j < 2; ++j)
#pragma unroll
      for (int kt = 0; kt < 4; ++kt)
        wb[j][kt] = WF[((wn * 2 + j) * 4 + kt) * 64 + l];
#pragma unroll
    for (int kt = 0; kt < 4; ++kt) pw4[kt] = PF[(wn * 4 + kt) * 64 + l];
#pragma unroll
    for (int j = 0; j < 2; ++j)
#pragma unroll
      for (int kt = 0; kt < 2; ++kt)
        itb[j][kt] = IF[((b * 8 + wn * 2 + j) * 2 + kt) * 64 + l];
    // A-fragments from global x (L2-hot: same rows as phase 1)
    bf16x8 afr[2][4];
#pragma unroll
    for (int h = 0; h < 2; ++h) {
      const float* xr = x + (size_t)(rows0 + wm * 32 + h * 16 + lr) * C + lq * 8;
#pragma unroll
      for (int kt = 0; kt < 4; ++kt) {
        f32x4 v0 = *(const f32x4*)(xr + kt * 32);
        f32x4 v1 = *(const f32x4*)(xr + kt * 32 + 4);
        bf16x8 pv;
#pragma unroll
        for (int q = 0; q < 4; ++q) {
          pv[q] = (short)f2b(v0[q]);
          pv[q + 4] = (short)f2b(v1[q]);
        }
        afr[h][kt] = pv;
      }
    }
    float wbias0 = W_b[wn * 32 + lr], wbias1 = W_b[wn * 32 + 16 + lr];
    float pbias = phi_b[wn * 16 + lr];
    f32x4 acc[2][2], pacc[2];
#pragma unroll
    for (int i = 0; i < 2; ++i) {
      acc[i][0] = (f32x4)(wbias0);
      acc[i][1] = (f32x4)(wbias1);
      pacc[i] = (f32x4)(pbias);
    }
#pragma unroll
    for (int kt = 0; kt < 4; ++kt) {
      pacc[0] = MFMA(afr[0][kt], pw4[kt], pacc[0]);
      pacc[1] = MFMA(afr[1][kt], pw4[kt], pacc[1]);
      acc[0][0] = MFMA(afr[0][kt], wb[0][kt], acc[0][0]);
      acc[0][1] = MFMA(afr[0][kt], wb[1][kt], acc[0][1]);
      acc[1][0] = MFMA(afr[1][kt], wb[0][kt], acc[1][0]);
      acc[1][1] = MFMA(afr[1][kt], wb[1][kt], acc[1][1]);
    }
#pragma unroll
    for (int i = 0; i < 2; ++i)
#pragma unroll
      for (int q = 0; q < 4; ++q) {
        int row = wm * 32 + i * 16 + lq * 4 + q;
        phT[row * 72 + wn * 16 + lr] = (short)f2b(pacc[i][q]);
      }
    __syncthreads();
#pragma unroll
    for (int kt = 0; kt < 2; ++kt) {
      bf16x8 p0 = *(const bf16x8*)(&phT[(wm * 32 + lr) * 72 + kt * 32 + lq * 8]);
      bf16x8 p1 =
          *(const bf16x8*)(&phT[(wm * 32 + 16 + lr) * 72 + kt * 32 + lq * 8]);
      acc[0][0] = MFMA(p0, itb[0][kt], acc[0][0]);
      acc[0][1] = MFMA(p0, itb[1][kt], acc[0][1]);
      acc[1][0] = MFMA(p1, itb[0][kt], acc[1][0]);
      acc[1][1] = MFMA(p1, itb[1][kt], acc[1][1]);
    }
#pragma unroll
    for (int i = 0; i < 2; ++i)
#pragma unroll
      for (int j = 0; j < 2; ++j)
#pragma unroll
        for (int q = 0; q < 4; ++q) {
          int row = rows0 + wm * 32 + i * 16 + lq * 4 + q;
          int col = wn * 32 + j * 16 + lr;
          out[(size_t)row * C + col] = gelu_fast(acc[i][j][q]);
        }
  }
}

extern "C" void kernel_launch(void* const* d_in, const int* in_sizes, int n_in,
                              void* d_out, int out_size, void* d_ws, size_t ws_size,
                              hipStream_t stream) {
  const float* x     = (const float*)d_in[0];
  const float* W_w   = (const float*)d_in[1];
  const float* W_b   = (const float*)d_in[2];
  const float* phi_w = (const float*)d_in[3];
  const float* phi_b = (const float*)d_in[4];
  const float* psi_w = (const float*)d_in[5];
  const float* psi_b = (const float*)d_in[6];
  float* out = (float*)d_out;

  // ws: partG[256*16384 bf16] | partS[256*128 f32] | gsumG[2*16384 f32]
  //     | gsumS[256 f32] | wtf[16384 bf16] | pwf[8192 bf16] | itf[16384 bf16]
  //     | bar[1 u32]
  unsigned short* partG = (unsigned short*)d_ws;
  float* partS = (float*)(partG + (size_t)BATCH * NCHUNK * C * C);
  float* gsumG = partS + (size_t)BATCH * NCHUNK * C;
  float* gsumS = gsumG + BATCH * C * C;
  unsigned short* wtf = (unsigned short*)(gsumS + BATCH * C);
  unsigned short* pwf = wtf + 16384;
  unsigned short* itf = pwf + 8192;
  unsigned* bar = (unsigned*)(itf + 16384);

  hipMemsetAsync(bar, 0, sizeof(unsigned), stream);
  k_fused<<<NBLK, 512, 0, stream>>>(x, W_w, W_b, phi_w, phi_b, psi_w, psi_b,
                                    out, partG, partS, gsumG, gsumS, wtf, pwf,
                                    itf, bar);
}

// Round 7
// 65.052 us; speedup vs baseline: 1.4201x; 1.2718x over previous
//
#include <hip/hip_runtime.h>
#include <hip/hip_bf16.h>
#include <math.h>

#define C 128
#define RANK 64
#define NB 8192
#define BATCH 2
#define NCHUNK 128                 // 64-row chunks per batch
#define NBLK 256                   // persistent blocks (1 per CU)
#define FSTRIDE 16                 // flag slot stride in u32 (64 B apart)

typedef float f32x4 __attribute__((ext_vector_type(4)));
typedef short bf16x8 __attribute__((ext_vector_type(8)));
typedef unsigned short u16x4 __attribute__((ext_vector_type(4)));

__device__ __forceinline__ unsigned short f2b(float f) {
  __hip_bfloat16 h = __float2bfloat16(f);
  return *reinterpret_cast<unsigned short*>(&h);
}
__device__ __forceinline__ float b2f(unsigned short h) {
  union { unsigned u; float f; } v; v.u = ((unsigned)h) << 16;
  return v.f;
}
// cubic-tanh GELU, branch-free, |err| <= ~1e-3 vs exact erf form
__device__ __forceinline__ float gelu_fast(float y) {
  float u = y * (1.0f + 0.044715f * y * y);
  float e = __expf(1.5957691216057308f * u);
  float t = 1.0f - 2.0f / (e + 1.0f);
  return 0.5f * y * (1.0f + t);
}
#define MFMA(a, b, c) __builtin_amdgcn_mfma_f32_16x16x32_bf16(a, b, c, 0, 0, 0)

// Grid barrier with ZERO atomic RMWs (same-line RMW serialization was ~23us
// per barrier with a single counter). Fan-in: per-block flag stores to
// 64B-spaced slots; master block 0 polls all flags then publishes epoch;
// everyone polls epoch. One release fence before flag store, one acquire
// fence after epoch observed.
__device__ __forceinline__ void gbar(unsigned* flags, unsigned* epoch, int e,
                                     unsigned p) {
  __syncthreads();
  if (threadIdx.x == 0) {
    __threadfence();   // release: write back dirty L2 before signaling
    __hip_atomic_store(&flags[e * FSTRIDE], p, __ATOMIC_RELAXED,
                       __HIP_MEMORY_SCOPE_AGENT);
  }
  if (e == 0) {
    if (threadIdx.x < NBLK) {
      while (__hip_atomic_load(&flags[threadIdx.x * FSTRIDE], __ATOMIC_RELAXED,
                               __HIP_MEMORY_SCOPE_AGENT) < p)
        __builtin_amdgcn_s_sleep(2);
    }
    __syncthreads();
    if (threadIdx.x == 0)
      __hip_atomic_store(epoch, p, __ATOMIC_RELAXED, __HIP_MEMORY_SCOPE_AGENT);
  }
  if (threadIdx.x == 0) {
    while (__hip_atomic_load(epoch, __ATOMIC_RELAXED,
                             __HIP_MEMORY_SCOPE_AGENT) < p)
      __builtin_amdgcn_s_sleep(2);
    __threadfence();   // acquire: invalidate once before reading peers' data
  }
  __syncthreads();
}

// ---------------------------------------------------------------------------
// Fused persistent kernel, 256 blocks x 512 threads.
// P1: Gram partial (64 rows/block, MFMA) + colsum; blocks 250-255 also pack
//     W_w/phi_w into bf16 fragment order.           -> barrier(1)
// P2a: reduce partG -> gsumG; blocks 248-249 reduce partS.  -> barrier(2)
// P2b: integral (r, 32-col slab per block) -> itf.          -> barrier(3)
// P3: rows [64e,64e+64): T1 phi=x*phi_w+phi_b; T2 acc=x*W_w+W_b;
//     T3 acc+=phi*integ; out=gelu_fast(acc).
// Fragment order: o = ((nt*KT+kt)*64 + lane)*8 + j holds
//   B[k = kt*32 + (lane>>4)*8 + j][n = nt*16 + (lane&15)].
// ---------------------------------------------------------------------------
__global__ __launch_bounds__(512, 1) void k_fused(
    const float* __restrict__ x, const float* __restrict__ W_w,
    const float* __restrict__ W_b, const float* __restrict__ phi_w,
    const float* __restrict__ phi_b, const float* __restrict__ psi_w,
    const float* __restrict__ psi_b, float* __restrict__ out,
    unsigned short* __restrict__ partG, float* __restrict__ partS,
    float* __restrict__ gsumG, float* __restrict__ gsumS,
    unsigned short* __restrict__ wtf, unsigned short* __restrict__ pwf,
    unsigned short* __restrict__ itf, unsigned* __restrict__ flags,
    unsigned* __restrict__ epoch) {
  __shared__ short xsT[C * 76];
  __shared__ float csp[4][C];
  __shared__ f32x4 red[512];
  __shared__ float psred[4][C];
  __shared__ float red2[2][16][32];
  __shared__ short phT[64 * 72];

  const int e = blockIdx.x;
  const int tid = threadIdx.x;
  const int l = tid & 63, w = tid >> 6;
  const int lr = l & 15, lq = l >> 4;

  // ================= Phase 1: Gram partial =================
  {
    const int b = e >> 7, chunk = e & 127;
    const float* xb = x + ((size_t)(b * NB + chunk * 64)) * C;
    const int c = tid & 127, ng = tid >> 7;
    float cs = 0.f;
#pragma unroll
    for (int it = 0; it < 4; ++it) {
      int n0 = it * 16 + ng * 4;
      u16x4 pv;
#pragma unroll
      for (int q = 0; q < 4; ++q) {
        float v = xb[(size_t)(n0 + q) * C + c];
        cs += v;
        pv[q] = f2b(v);
      }
      *(u16x4*)(&xsT[c * 76 + n0]) = pv;
    }
    csp[ng][c] = cs;
    __syncthreads();
    f32x4 acc[8];
#pragma unroll
    for (int tj = 0; tj < 8; ++tj) acc[tj] = (f32x4)(0.f);
    bf16x8 af[2];
#pragma unroll
    for (int kk = 0; kk < 2; ++kk)
      af[kk] = *(const bf16x8*)(&xsT[(w * 16 + lr) * 76 + kk * 32 + lq * 8]);
#pragma unroll
    for (int tj = 0; tj < 8; ++tj)
#pragma unroll
      for (int kk = 0; kk < 2; ++kk) {
        bf16x8 bfr = *(const bf16x8*)(&xsT[(tj * 16 + lr) * 76 + kk * 32 + lq * 8]);
        acc[tj] = MFMA(af[kk], bfr, acc[tj]);
      }
    unsigned short* dst = partG + (size_t)e * (C * C);
#pragma unroll
    for (int tj = 0; tj < 8; ++tj)
#pragma unroll
      for (int q = 0; q < 4; ++q) {
        int ci = w * 16 + lq * 4 + q;
        int cj = tj * 16 + lr;
        dst[ci * C + cj] = f2b(acc[tj][q]);
      }
    if (tid < C)
      partS[e * C + tid] = csp[0][tid] + csp[1][tid] + csp[2][tid] + csp[3][tid];
    // packing off the master block: 250-253 -> wtf, 254-255 -> pwf
    if (e >= 250 && e < 254) {
      int o0 = (e - 250) * 4096 + tid * 8;
#pragma unroll
      for (int h = 0; h < 2; ++h) {
        u16x4 v;
#pragma unroll
        for (int q = 0; q < 4; ++q) {
          int o = o0 + h * 4 + q;
          int j = o & 7, lane = (o >> 3) & 63, kt = (o >> 9) & 3, nt = o >> 11;
          int n = nt * 16 + (lane & 15);
          int k = kt * 32 + ((lane >> 4) << 3) + j;
          v[q] = f2b(W_w[k * C + n]);
        }
        *(u16x4*)(wtf + o0 + h * 4) = v;
      }
    } else if (e >= 254) {
      int o0 = (e - 254) * 4096 + tid * 8;
#pragma unroll
      for (int h = 0; h < 2; ++h) {
        u16x4 v;
#pragma unroll
        for (int q = 0; q < 4; ++q) {
          int o = o0 + h * 4 + q;
          int j = o & 7, lane = (o >> 3) & 63, kt = (o >> 9) & 3, nt = o >> 11;
          int r = nt * 16 + (lane & 15);
          int c2 = kt * 32 + ((lane >> 4) << 3) + j;
          v[q] = f2b(phi_w[c2 * RANK + r]);
        }
        *(u16x4*)(pwf + o0 + h * 4) = v;
      }
    }
  }
  gbar(flags, epoch, e, 1u);

  // ================= Phase 2a: reduce partials =================
  {
    const int b = e >> 7, i0 = (e & 127) * 128;
    const int chg = tid >> 5, ig = tid & 31;   // 16 groups x 8 chunks
    f32x4 a = (f32x4)(0.f);
    const unsigned short* base =
        partG + (size_t)(b * NCHUNK + chg * 8) * (C * C) + i0 + ig * 4;
#pragma unroll
    for (int cc = 0; cc < 8; ++cc) {
      u16x4 v = *(const u16x4*)(base + (size_t)cc * (C * C));
#pragma unroll
      for (int q = 0; q < 4; ++q) a[q] += b2f(v[q]);
    }
    red[tid] = a;
    if (e >= 248 && e < 250) {  // partS reduce for batch e-248
      const int bb = e - 248;
      const int grp = tid >> 7, cloc = tid & 127;
      float s = 0.f;
#pragma unroll
      for (int cc = 0; cc < 32; ++cc)
        s += partS[(size_t)(bb * NCHUNK + grp * 32 + cc) * C + cloc];
      psred[grp][cloc] = s;
    }
    __syncthreads();
    if (tid < 32) {
      f32x4 s = red[tid];
#pragma unroll
      for (int g = 1; g < 16; ++g) {
        f32x4 r = red[g * 32 + tid];
#pragma unroll
        for (int q = 0; q < 4; ++q) s[q] += r[q];
      }
      *(f32x4*)(&gsumG[b * (C * C) + i0 + tid * 4]) = s;
    }
    if (e >= 248 && e < 250 && tid < C)
      gsumS[(e - 248) * C + tid] =
          psred[0][tid] + psred[1][tid] + psred[2][tid] + psred[3][tid];
  }
  gbar(flags, epoch, e, 2u);

  // ================= Phase 2b: integral -> itf =================
  {
    const int r = e >> 2, chq = e & 3;
    const int kg = tid >> 5, c32 = tid & 31;   // 16 groups x 8 k's
    const int c = chq * 32 + c32;
    const float* psW = psi_w + (size_t)r * C + c;
    const float* G0 = gsumG + c;
    const float* G1 = gsumG + C * C + c;
    float a0 = 0.f, a1 = 0.f;
#pragma unroll
    for (int i = 0; i < 8; ++i) {
      int k = kg * 8 + i;
      float pw = psW[(size_t)k * (RANK * C)];
      a0 += pw * G0[k * C];
      a1 += pw * G1[k * C];
    }
    red2[0][kg][c32] = a0;
    red2[1][kg][c32] = a1;
    __syncthreads();
    if (tid < 64) {
      int b = tid >> 5, cc = tid & 31;
      float s = 0.f;
#pragma unroll
      for (int g = 0; g < 16; ++g) s += red2[b][g][cc];
      int cg = chq * 32 + cc;
      s += psi_b[r * C + cg] * gsumS[b * C + cg];
      s *= (1.0f / NB);
      int nt = cg >> 4, kt = r >> 5;
      int lane = ((r >> 3) & 3) * 16 + (cg & 15), j = r & 7;
      itf[(size_t)(((b * 8 + nt) * 2 + kt) * 64 + lane) * 8 + j] = f2b(s);
    }
  }
  gbar(flags, epoch, e, 3u);

  // ================= Phase 3: fused main =================
  {
    const int wm = w >> 2, wn = w & 3;
    const int rows0 = e * 64;
    const int b = e >> 7;
    bf16x8 wb[2][4], pw4[4], itb[2][2];
    const bf16x8* WF = (const bf16x8*)wtf;
    const bf16x8* PF = (const bf16x8*)pwf;
    const bf16x8* IF = (const bf16x8*)itf;
#pragma unroll
    for (int j = 0; j < 2; ++j)
#pragma unroll
      for (int kt = 0; kt < 4; ++kt)
        wb[j][kt] = WF[((wn * 2 + j) * 4 + kt) * 64 + l];
#pragma unroll
    for (int kt = 0; kt < 4; ++kt) pw4[kt] = PF[(wn * 4 + kt) * 64 + l];
#pragma unroll
    for (int j = 0; j < 2; ++j)
#pragma unroll
      for (int kt = 0; kt < 2; ++kt)
        itb[j][kt] = IF[((b * 8 + wn * 2 + j) * 2 + kt) * 64 + l];
    // A-fragments from global x
    bf16x8 afr[2][4];
#pragma unroll
    for (int h = 0; h < 2; ++h) {
      const float* xr = x + (size_t)(rows0 + wm * 32 + h * 16 + lr) * C + lq * 8;
#pragma unroll
      for (int kt = 0; kt < 4; ++kt) {
        f32x4 v0 = *(const f32x4*)(xr + kt * 32);
        f32x4 v1 = *(const f32x4*)(xr + kt * 32 + 4);
        bf16x8 pv;
#pragma unroll
        for (int q = 0; q < 4; ++q) {
          pv[q] = (short)f2b(v0[q]);
          pv[q + 4] = (short)f2b(v1[q]);
        }
        afr[h][kt] = pv;
      }
    }
    float wbias0 = W_b[wn * 32 + lr], wbias1 = W_b[wn * 32 + 16 + lr];
    float pbias = phi_b[wn * 16 + lr];
    f32x4 acc[2][2], pacc[2];
#pragma unroll
    for (int i = 0; i < 2; ++i) {
      acc[i][0] = (f32x4)(wbias0);
      acc[i][1] = (f32x4)(wbias1);
      pacc[i] = (f32x4)(pbias);
    }
#pragma unroll
    for (int kt = 0; kt < 4; ++kt) {
      pacc[0] = MFMA(afr[0][kt], pw4[kt], pacc[0]);
      pacc[1] = MFMA(afr[1][kt], pw4[kt], pacc[1]);
      acc[0][0] = MFMA(afr[0][kt], wb[0][kt], acc[0][0]);
      acc[0][1] = MFMA(afr[0][kt], wb[1][kt], acc[0][1]);
      acc[1][0] = MFMA(afr[1][kt], wb[0][kt], acc[1][0]);
      acc[1][1] = MFMA(afr[1][kt], wb[1][kt], acc[1][1]);
    }
#pragma unroll
    for (int i = 0; i < 2; ++i)
#pragma unroll
      for (int q = 0; q < 4; ++q) {
        int row = wm * 32 + i * 16 + lq * 4 + q;
        phT[row * 72 + wn * 16 + lr] = (short)f2b(pacc[i][q]);
      }
    __syncthreads();
#pragma unroll
    for (int kt = 0; kt < 2; ++kt) {
      bf16x8 p0 = *(const bf16x8*)(&phT[(wm * 32 + lr) * 72 + kt * 32 + lq * 8]);
      bf16x8 p1 =
          *(const bf16x8*)(&phT[(wm * 32 + 16 + lr) * 72 + kt * 32 + lq * 8]);
      acc[0][0] = MFMA(p0, itb[0][kt], acc[0][0]);
      acc[0][1] = MFMA(p0, itb[1][kt], acc[0][1]);
      acc[1][0] = MFMA(p1, itb[0][kt], acc[1][0]);
      acc[1][1] = MFMA(p1, itb[1][kt], acc[1][1]);
    }
#pragma unroll
    for (int i = 0; i < 2; ++i)
#pragma unroll
      for (int j = 0; j < 2; ++j)
#pragma unroll
        for (int q = 0; q < 4; ++q) {
          int row = rows0 + wm * 32 + i * 16 + lq * 4 + q;
          int col = wn * 32 + j * 16 + lr;
          out[(size_t)row * C + col] = gelu_fast(acc[i][j][q]);
        }
  }
}

extern "C" void kernel_launch(void* const* d_in, const int* in_sizes, int n_in,
                              void* d_out, int out_size, void* d_ws, size_t ws_size,
                              hipStream_t stream) {
  const float* x     = (const float*)d_in[0];
  const float* W_w   = (const float*)d_in[1];
  const float* W_b   = (const float*)d_in[2];
  const float* phi_w = (const float*)d_in[3];
  const float* phi_b = (const float*)d_in[4];
  const float* psi_w = (const float*)d_in[5];
  const float* psi_b = (const float*)d_in[6];
  float* out = (float*)d_out;

  // ws: partG[256*16384 bf16] | partS[256*128 f32] | gsumG[2*16384 f32]
  //     | gsumS[256 f32] | wtf[16384 bf16] | pwf[8192 bf16] | itf[16384 bf16]
  //     | flags[256*16 u32] | epoch[1 u32]
  unsigned short* partG = (unsigned short*)d_ws;
  float* partS = (float*)(partG + (size_t)BATCH * NCHUNK * C * C);
  float* gsumG = partS + (size_t)BATCH * NCHUNK * C;
  float* gsumS = gsumG + BATCH * C * C;
  unsigned short* wtf = (unsigned short*)(gsumS + BATCH * C);
  unsigned short* pwf = wtf + 16384;
  unsigned short* itf = pwf + 8192;
  unsigned* flags = (unsigned*)(itf + 16384);
  unsigned* epoch = flags + NBLK * FSTRIDE;

  hipMemsetAsync(flags, 0, (NBLK * FSTRIDE + 1) * sizeof(unsigned), stream);
  k_fused<<<NBLK, 512, 0, stream>>>(x, W_w, W_b, phi_w, phi_b, psi_w, psi_b,
                                    out, partG, partS, gsumG, gsumS, wtf, pwf,
                                    itf, flags, epoch);
}

// Round 8
// 57.769 us; speedup vs baseline: 1.5991x; 1.1261x over previous
//
#include <hip/hip_runtime.h>
#include <hip/hip_bf16.h>
#include <math.h>

#define C 128
#define RANK 64
#define NB 8192
#define BATCH 2
#define NCHUNK 128                 // 64-row chunks per batch
#define FSCALE 16777216.0f         // 2^24 fixed-point scale
#define INV_FSCALE (1.0f / 16777216.0f)

typedef float f32x4 __attribute__((ext_vector_type(4)));
typedef short bf16x8 __attribute__((ext_vector_type(8)));
typedef unsigned short u16x4 __attribute__((ext_vector_type(4)));
typedef unsigned long long u64;

__device__ __forceinline__ unsigned short f2b(float f) {
  __hip_bfloat16 h = __float2bfloat16(f);
  return *reinterpret_cast<unsigned short*>(&h);
}
// cubic-tanh GELU, branch-free, |err| <= ~1e-3 vs exact erf form
__device__ __forceinline__ float gelu_fast(float y) {
  float u = y * (1.0f + 0.044715f * y * y);
  float e = __expf(1.5957691216057308f * u);
  float t = 1.0f - 2.0f / (e + 1.0f);
  return 0.5f * y * (1.0f + t);
}
__device__ __forceinline__ void atomAddI64(u64* p, float v) {
  long long q = (long long)llrintf(v * FSCALE);   // exact, deterministic
  atomicAdd(p, (u64)q);                           // 2's-complement int add commutes
}
__device__ __forceinline__ float rdI64(const u64* p) {
  return (float)(long long)(*p) * INV_FSCALE;
}
#define MFMA(a, b, c) __builtin_amdgcn_mfma_f32_16x16x32_bf16(a, b, c, 0, 0, 0)

// ---------------------------------------------------------------------------
// k_gram: blocks [0,256): 64-row Gram partial via MFMA (8 waves); partial
// accumulated into global int64 fixed-point via atomicAdd (deterministic).
// Blocks [256,268): pack W_w / phi_w into bf16 fragment order.
// Fragment order: o = ((nt*KT+kt)*64 + lane)*8 + j holds
//   B[k = kt*32 + (lane>>4)*8 + j][n = nt*16 + (lane&15)].
// ---------------------------------------------------------------------------
__global__ __launch_bounds__(512) void k_gram(
    const float* __restrict__ x, u64* __restrict__ gsumGI,
    u64* __restrict__ gsumSI,
    unsigned short* __restrict__ wtf, unsigned short* __restrict__ pwf,
    const float* __restrict__ W_w, const float* __restrict__ phi_w) {
  const int blk = blockIdx.x;
  const int tid = threadIdx.x;
  if (blk >= BATCH * NCHUNK) {
    const int p = blk - BATCH * NCHUNK;
    if (p < 8) {   // W_w -> wtf, 16384 elems
      int o0 = p * 2048 + tid * 4;
      u16x4 v;
#pragma unroll
      for (int q = 0; q < 4; ++q) {
        int o = o0 + q;
        int j = o & 7, lane = (o >> 3) & 63, kt = (o >> 9) & 3, nt = o >> 11;
        int n = nt * 16 + (lane & 15);
        int k = kt * 32 + ((lane >> 4) << 3) + j;
        v[q] = f2b(W_w[k * C + n]);
      }
      *(u16x4*)(wtf + o0) = v;
    } else {       // phi_w -> pwf, 8192 elems
      int o0 = (p - 8) * 2048 + tid * 4;
      u16x4 v;
#pragma unroll
      for (int q = 0; q < 4; ++q) {
        int o = o0 + q;
        int j = o & 7, lane = (o >> 3) & 63, kt = (o >> 9) & 3, nt = o >> 11;
        int r = nt * 16 + (lane & 15);
        int c = kt * 32 + ((lane >> 4) << 3) + j;
        v[q] = f2b(phi_w[c * RANK + r]);
      }
      *(u16x4*)(pwf + o0) = v;
    }
    return;
  }
  __shared__ short xsT[C * 76];     // [c][n], stride 76: aligned + conflict-free
  __shared__ float csp[4][C];
  const int b = blk >> 7, chunk = blk & 127;
  const float* xb = x + ((size_t)(b * NB + chunk * 64)) * C;
  {
    const int c = tid & 127, ng = tid >> 7;   // ng 0..3
    float cs = 0.f;
#pragma unroll
    for (int it = 0; it < 4; ++it) {
      int n0 = it * 16 + ng * 4;
      u16x4 pv;
#pragma unroll
      for (int q = 0; q < 4; ++q) {
        float v = xb[(size_t)(n0 + q) * C + c];
        cs += v;
        pv[q] = f2b(v);
      }
      *(u16x4*)(&xsT[c * 76 + n0]) = pv;
    }
    csp[ng][c] = cs;
  }
  __syncthreads();
  const int l = tid & 63, w = tid >> 6;       // 8 waves, wave = 16-row G tile
  const int lr = l & 15, lq = l >> 4;
  f32x4 acc[8];
#pragma unroll
  for (int tj = 0; tj < 8; ++tj) acc[tj] = (f32x4)(0.f);
  bf16x8 af[2];
#pragma unroll
  for (int kk = 0; kk < 2; ++kk)
    af[kk] = *(const bf16x8*)(&xsT[(w * 16 + lr) * 76 + kk * 32 + lq * 8]);
#pragma unroll
  for (int tj = 0; tj < 8; ++tj)
#pragma unroll
    for (int kk = 0; kk < 2; ++kk) {
      bf16x8 bfr = *(const bf16x8*)(&xsT[(tj * 16 + lr) * 76 + kk * 32 + lq * 8]);
      acc[tj] = MFMA(af[kk], bfr, acc[tj]);
    }
  u64* dst = gsumGI + (size_t)b * (C * C);
#pragma unroll
  for (int tj = 0; tj < 8; ++tj)
#pragma unroll
    for (int q = 0; q < 4; ++q) {
      int ci = w * 16 + lq * 4 + q;
      int cj = tj * 16 + lr;
      atomAddI64(&dst[ci * C + cj], acc[tj][q]);
    }
  __syncthreads();
  if (tid < C)
    atomAddI64(&gsumSI[b * C + tid],
               csp[0][tid] + csp[1][tid] + csp[2][tid] + csp[3][tid]);
}

// ---------------------------------------------------------------------------
// k_integral: integ[b][r][c] = (sum_k psiw[k][r*C+c]*G[b][k][c]
//                               + psib[r*C+c]*S[b][c]) / NB -> itf (bf16 frag)
// grid (r=64, ch=4), 256 threads = kg(8) x c32(32); both batches per thread.
// G read from int64 fixed-point accumulator.
// ---------------------------------------------------------------------------
__global__ __launch_bounds__(256) void k_integral(
    const float* __restrict__ psi_w, const float* __restrict__ psi_b,
    const u64* __restrict__ gsumGI, const u64* __restrict__ gsumSI,
    unsigned short* __restrict__ itf) {
  __shared__ float red[2][8][32];
  const int r = blockIdx.x, ch = blockIdx.y;
  const int tid = threadIdx.x, kg = tid >> 5, c32 = tid & 31;
  const int c = ch * 32 + c32;
  const float* psW = psi_w + (size_t)r * C + c;
  const u64* G0 = gsumGI + c;
  const u64* G1 = gsumGI + C * C + c;
  float a0 = 0.f, a1 = 0.f;
#pragma unroll
  for (int i = 0; i < 16; ++i) {
    int k = kg * 16 + i;
    float pw = psW[(size_t)k * (RANK * C)];
    a0 += pw * rdI64(&G0[k * C]);
    a1 += pw * rdI64(&G1[k * C]);
  }
  red[0][kg][c32] = a0;
  red[1][kg][c32] = a1;
  __syncthreads();
  if (tid < 64) {
    int b = tid >> 5, cc = tid & 31;
    float s = 0.f;
#pragma unroll
    for (int g = 0; g < 8; ++g) s += red[b][g][cc];
    int cg = ch * 32 + cc;
    s += psi_b[r * C + cg] * rdI64(&gsumSI[b * C + cg]);
    s *= (1.0f / NB);
    int nt = cg >> 4, kt = r >> 5;
    int lane = ((r >> 3) & 3) * 16 + (cg & 15), j = r & 7;
    itf[(size_t)(((b * 8 + nt) * 2 + kt) * 64 + lane) * 8 + j] = f2b(s);
  }
}

// ---------------------------------------------------------------------------
// k_main: 32 rows/block, 256 threads (4 waves = 4 col-tiles), MFMA fused.
// A-fragments loaded directly from row-major f32 x (L3-warm), converted
// in-register; single barrier (phi exchange).
//   T1 phi = x*phi_w + phi_b ; T2 acc = x*W_w + W_b ; T3 acc += phi*integ
//   out = gelu_fast(acc)
// ---------------------------------------------------------------------------
__global__ __launch_bounds__(256, 2) void k_main(
    const float* __restrict__ x, const float* __restrict__ W_b,
    const float* __restrict__ phi_b, const unsigned short* __restrict__ wtf,
    const unsigned short* __restrict__ pwf, const unsigned short* __restrict__ itf,
    float* __restrict__ out) {
  __shared__ short phT[32 * 72];
  const int tid = threadIdx.x, l = tid & 63, wn = tid >> 6;
  const int row0 = blockIdx.x * 32;
  const int b = blockIdx.x >> 8;
  const int lr = l & 15, lq = l >> 4;
  bf16x8 wb[2][4], pw[4], itb[2][2];
  const bf16x8* WF = (const bf16x8*)wtf;
  const bf16x8* PF = (const bf16x8*)pwf;
  const bf16x8* IF = (const bf16x8*)itf;
#pragma unroll
  for (int j = 0; j < 2; ++j)
#pragma unroll
    for (int kt = 0; kt < 4; ++kt)
      wb[j][kt] = WF[((wn * 2 + j) * 4 + kt) * 64 + l];
#pragma unroll
  for (int kt = 0; kt < 4; ++kt) pw[kt] = PF[(wn * 4 + kt) * 64 + l];
#pragma unroll
  for (int j = 0; j < 2; ++j)
#pragma unroll
    for (int kt = 0; kt < 2; ++kt)
      itb[j][kt] = IF[((b * 8 + wn * 2 + j) * 2 + kt) * 64 + l];
  bf16x8 afr[2][4];
#pragma unroll
  for (int h = 0; h < 2; ++h) {
    const float* xr = x + (size_t)(row0 + h * 16 + lr) * C + lq * 8;
#pragma unroll
    for (int kt = 0; kt < 4; ++kt) {
      f32x4 v0 = *(const f32x4*)(xr + kt * 32);
      f32x4 v1 = *(const f32x4*)(xr + kt * 32 + 4);
      bf16x8 pv;
#pragma unroll
      for (int q = 0; q < 4; ++q) {
        pv[q] = (short)f2b(v0[q]);
        pv[q + 4] = (short)f2b(v1[q]);
      }
      afr[h][kt] = pv;
    }
  }
  float wb0 = W_b[wn * 32 + lr], wb1 = W_b[wn * 32 + 16 + lr];
  float pb0 = phi_b[wn * 16 + lr];
  f32x4 acc[2][2], pacc[2];
#pragma unroll
  for (int i = 0; i < 2; ++i) {
    acc[i][0] = (f32x4)(wb0);
    acc[i][1] = (f32x4)(wb1);
    pacc[i] = (f32x4)(pb0);
  }
#pragma unroll
  for (int kt = 0; kt < 4; ++kt) {
    pacc[0] = MFMA(afr[0][kt], pw[kt], pacc[0]);
    pacc[1] = MFMA(afr[1][kt], pw[kt], pacc[1]);
    acc[0][0] = MFMA(afr[0][kt], wb[0][kt], acc[0][0]);
    acc[0][1] = MFMA(afr[0][kt], wb[1][kt], acc[0][1]);
    acc[1][0] = MFMA(afr[1][kt], wb[0][kt], acc[1][0]);
    acc[1][1] = MFMA(afr[1][kt], wb[1][kt], acc[1][1]);
  }
#pragma unroll
  for (int i = 0; i < 2; ++i)
#pragma unroll
    for (int q = 0; q < 4; ++q) {
      int row = i * 16 + lq * 4 + q;
      phT[row * 72 + wn * 16 + lr] = (short)f2b(pacc[i][q]);
    }
  __syncthreads();
#pragma unroll
  for (int kt = 0; kt < 2; ++kt) {
    bf16x8 p0 = *(const bf16x8*)(&phT[lr * 72 + kt * 32 + lq * 8]);
    bf16x8 p1 = *(const bf16x8*)(&phT[(16 + lr) * 72 + kt * 32 + lq * 8]);
    acc[0][0] = MFMA(p0, itb[0][kt], acc[0][0]);
    acc[0][1] = MFMA(p0, itb[1][kt], acc[0][1]);
    acc[1][0] = MFMA(p1, itb[0][kt], acc[1][0]);
    acc[1][1] = MFMA(p1, itb[1][kt], acc[1][1]);
  }
#pragma unroll
  for (int i = 0; i < 2; ++i)
#pragma unroll
    for (int j = 0; j < 2; ++j)
#pragma unroll
      for (int q = 0; q < 4; ++q) {
        int row = row0 + i * 16 + lq * 4 + q;
        int col = wn * 32 + j * 16 + lr;
        out[(size_t)row * C + col] = gelu_fast(acc[i][j][q]);
      }
}

extern "C" void kernel_launch(void* const* d_in, const int* in_sizes, int n_in,
                              void* d_out, int out_size, void* d_ws, size_t ws_size,
                              hipStream_t stream) {
  const float* x     = (const float*)d_in[0];
  const float* W_w   = (const float*)d_in[1];
  const float* W_b   = (const float*)d_in[2];
  const float* phi_w = (const float*)d_in[3];
  const float* phi_b = (const float*)d_in[4];
  const float* psi_w = (const float*)d_in[5];
  const float* psi_b = (const float*)d_in[6];
  float* out = (float*)d_out;

  // ws: gsumGI[2*16384 u64] | gsumSI[2*128 u64] | wtf[16384 bf16]
  //     | pwf[8192 bf16] | itf[16384 bf16]
  u64* gsumGI = (u64*)d_ws;
  u64* gsumSI = gsumGI + (size_t)BATCH * C * C;
  unsigned short* wtf = (unsigned short*)(gsumSI + BATCH * C);
  unsigned short* pwf = wtf + 16384;
  unsigned short* itf = pwf + 8192;

  const size_t accum_bytes = ((size_t)BATCH * C * C + BATCH * C) * sizeof(u64);
  hipMemsetAsync(gsumGI, 0, accum_bytes, stream);
  k_gram<<<BATCH * NCHUNK + 12, 512, 0, stream>>>(x, gsumGI, gsumSI, wtf, pwf,
                                                  W_w, phi_w);
  k_integral<<<dim3(RANK, 4), 256, 0, stream>>>(psi_w, psi_b, gsumGI, gsumSI,
                                                itf);
  k_main<<<(BATCH * NB) / 32, 256, 0, stream>>>(x, W_b, phi_b, wtf, pwf, itf,
                                                out);
}

// Round 9
// 26.190 us; speedup vs baseline: 3.5274x; 2.2058x over previous
//
#include <hip/hip_runtime.h>
#include <hip/hip_bf16.h>
#include <math.h>

#define C 128
#define RANK 64
#define NB 8192
#define BATCH 2
#define NCHUNK 128                 // 64-row chunks per batch

typedef float f32x4 __attribute__((ext_vector_type(4)));
typedef short bf16x8 __attribute__((ext_vector_type(8)));
typedef unsigned short u16x4 __attribute__((ext_vector_type(4)));

__device__ __forceinline__ unsigned short f2b(float f) {
  __hip_bfloat16 h = __float2bfloat16(f);
  return *reinterpret_cast<unsigned short*>(&h);
}
__device__ __forceinline__ float b2f(unsigned short h) {
  union { unsigned u; float f; } v; v.u = ((unsigned)h) << 16;
  return v.f;
}
// cubic-tanh GELU; rcp approx (1 ULP) instead of exact divide
__device__ __forceinline__ float gelu_fast(float y) {
  float u = y * (1.0f + 0.044715f * y * y);
  float e = __expf(1.5957691216057308f * u);     // e^{2*0.7978845608*u}
  float t = 1.0f - 2.0f * __builtin_amdgcn_rcpf(e + 1.0f);
  return 0.5f * y * (1.0f + t);
}
#define MFMA(a, b, c) __builtin_amdgcn_mfma_f32_16x16x32_bf16(a, b, c, 0, 0, 0)

// ---------------------------------------------------------------------------
// k_gram: blocks [0,256): 64-row Gram partial via MFMA (8 waves), stored as
// bf16 in MFMA C-FRAGMENT FLAT ORDER: fidx(w,tj,l,q) = (w*8+tj)*256 + l*4 + q
// holding G[ci=w*16+(l>>4)*4+q][cj=tj*16+(l&15)]. Lane-contiguous u16x4
// stores = perfect coalescing. f32 column-sum partial unchanged.
// Blocks [256,268): pack W_w / phi_w into bf16 MFMA B-fragment order:
//   o = ((nt*KT+kt)*64 + lane)*8 + j  holds
//   B[k = kt*32 + (lane>>4)*8 + j][n = nt*16 + (lane&15)].
// ---------------------------------------------------------------------------
__global__ __launch_bounds__(512) void k_gram(
    const float* __restrict__ x, unsigned short* __restrict__ partG,
    float* __restrict__ partS,
    unsigned short* __restrict__ wtf, unsigned short* __restrict__ pwf,
    const float* __restrict__ W_w, const float* __restrict__ phi_w) {
  const int blk = blockIdx.x;
  const int tid = threadIdx.x;
  if (blk >= BATCH * NCHUNK) {
    const int p = blk - BATCH * NCHUNK;
    if (p < 8) {   // W_w -> wtf, 16384 elems
      int o0 = p * 2048 + tid * 4;
      u16x4 v;
#pragma unroll
      for (int q = 0; q < 4; ++q) {
        int o = o0 + q;
        int j = o & 7, lane = (o >> 3) & 63, kt = (o >> 9) & 3, nt = o >> 11;
        int n = nt * 16 + (lane & 15);
        int k = kt * 32 + ((lane >> 4) << 3) + j;
        v[q] = f2b(W_w[k * C + n]);
      }
      *(u16x4*)(wtf + o0) = v;
    } else {       // phi_w -> pwf, 8192 elems
      int o0 = (p - 8) * 2048 + tid * 4;
      u16x4 v;
#pragma unroll
      for (int q = 0; q < 4; ++q) {
        int o = o0 + q;
        int j = o & 7, lane = (o >> 3) & 63, kt = (o >> 9) & 3, nt = o >> 11;
        int r = nt * 16 + (lane & 15);
        int c = kt * 32 + ((lane >> 4) << 3) + j;
        v[q] = f2b(phi_w[c * RANK + r]);
      }
      *(u16x4*)(pwf + o0) = v;
    }
    return;
  }
  __shared__ short xsT[C * 76];     // [c][n], stride 76: aligned + conflict-free
  __shared__ float csp[4][C];
  const int b = blk >> 7, chunk = blk & 127;
  const float* xb = x + ((size_t)(b * NB + chunk * 64)) * C;
  {
    const int c = tid & 127, ng = tid >> 7;   // ng 0..3
    float cs = 0.f;
#pragma unroll
    for (int it = 0; it < 4; ++it) {
      int n0 = it * 16 + ng * 4;
      u16x4 pv;
#pragma unroll
      for (int q = 0; q < 4; ++q) {
        float v = xb[(size_t)(n0 + q) * C + c];
        cs += v;
        pv[q] = f2b(v);
      }
      *(u16x4*)(&xsT[c * 76 + n0]) = pv;
    }
    csp[ng][c] = cs;
  }
  __syncthreads();
  const int l = tid & 63, w = tid >> 6;       // 8 waves, wave = 16-row G tile
  const int lr = l & 15, lq = l >> 4;
  f32x4 acc[8];
#pragma unroll
  for (int tj = 0; tj < 8; ++tj) acc[tj] = (f32x4)(0.f);
  bf16x8 af[2];
#pragma unroll
  for (int kk = 0; kk < 2; ++kk)
    af[kk] = *(const bf16x8*)(&xsT[(w * 16 + lr) * 76 + kk * 32 + lq * 8]);
#pragma unroll
  for (int tj = 0; tj < 8; ++tj)
#pragma unroll
    for (int kk = 0; kk < 2; ++kk) {
      bf16x8 bfr = *(const bf16x8*)(&xsT[(tj * 16 + lr) * 76 + kk * 32 + lq * 8]);
      acc[tj] = MFMA(af[kk], bfr, acc[tj]);
    }
  // store in fragment order: lane-contiguous u16x4 (8B) per tj
  unsigned short* dst = partG + (size_t)blk * (C * C);
#pragma unroll
  for (int tj = 0; tj < 8; ++tj) {
    u16x4 pv;
#pragma unroll
    for (int q = 0; q < 4; ++q) pv[q] = f2b(acc[tj][q]);
    *(u16x4*)(dst + (w * 8 + tj) * 256 + l * 4) = pv;
  }
  if (tid < C)
    partS[blk * C + tid] = csp[0][tid] + csp[1][tid] + csp[2][tid] + csp[3][tid];
}

// ---------------------------------------------------------------------------
// k_reduce: chunk-parallel, layout-agnostic elementwise sum.
// Blocks [0,256): b = e>>7, i0 = (e&127)*128; 256 thr = (chg 8) x (ig 32);
// each thread sums 16 chunks of u16x4; LDS tree. Blocks [256,258): partS.
// ---------------------------------------------------------------------------
__global__ __launch_bounds__(256) void k_reduce(
    const unsigned short* __restrict__ partG, const float* __restrict__ partS,
    float* __restrict__ gsumG, float* __restrict__ gsumS) {
  const int e = blockIdx.x, tid = threadIdx.x;
  if (e < 256) {
    __shared__ f32x4 red[256];
    const int b = e >> 7, i0 = (e & 127) * 128;
    const int chg = tid >> 5, ig = tid & 31;
    f32x4 a = (f32x4)(0.f);
    const unsigned short* base =
        partG + (size_t)(b * NCHUNK + chg * 16) * (C * C) + i0 + ig * 4;
#pragma unroll
    for (int cc = 0; cc < 16; ++cc) {
      u16x4 v = *(const u16x4*)(base + (size_t)cc * (C * C));
#pragma unroll
      for (int q = 0; q < 4; ++q) a[q] += b2f(v[q]);
    }
    red[tid] = a;
    __syncthreads();
    if (tid < 32) {
      f32x4 s = red[tid];
#pragma unroll
      for (int g = 1; g < 8; ++g) {
        f32x4 r = red[g * 32 + tid];
#pragma unroll
        for (int q = 0; q < 4; ++q) s[q] += r[q];
      }
      *(f32x4*)(&gsumG[b * (C * C) + i0 + tid * 4]) = s;
    }
  } else {
    __shared__ float s2[2][C];
    const int b = e - 256;
    const int c = tid & 127, half = tid >> 7;
    const float* p = partS + (size_t)(b * NCHUNK + half * 64) * C + c;
    float s = 0.f;
#pragma unroll
    for (int cc = 0; cc < 64; ++cc) s += p[(size_t)cc * C];
    s2[half][c] = s;
    __syncthreads();
    if (tid < C) gsumS[b * C + tid] = s2[0][tid] + s2[1][tid];
  }
}

// ---------------------------------------------------------------------------
// k_integral: integ[b][r][c] = (sum_k psiw[k][r*C+c]*G[b][k][c]
//                               + psib[r*C+c]*S[b][c]) / NB -> itf (bf16 frag)
// grid (r=64, ch=4), 256 threads = kg(8) x c32(32); both batches per thread.
// G is in fragment-flat order: 4 consecutive k (one q-group) = one f32x4.
//   fidx(k4,c) = ((k4>>2)*8 + (c>>4))*256 + ((k4&3)*16 + (c&15))*4
// ---------------------------------------------------------------------------
__global__ __launch_bounds__(256) void k_integral(
    const float* __restrict__ psi_w, const float* __restrict__ psi_b,
    const float* __restrict__ gsumG, const float* __restrict__ gsumS,
    unsigned short* __restrict__ itf) {
  __shared__ float red[2][8][32];
  const int r = blockIdx.x, ch = blockIdx.y;
  const int tid = threadIdx.x, kg = tid >> 5, c32 = tid & 31;
  const int c = ch * 32 + c32;
  const int tj = c >> 4, lr = c & 15;
  const float* psW = psi_w + (size_t)r * C + c;
  float a0 = 0.f, a1 = 0.f;
#pragma unroll
  for (int i = 0; i < 4; ++i) {
    int k4 = kg * 4 + i;               // k = k4*4 + q, q=0..3
    int fidx = ((k4 >> 2) * 8 + tj) * 256 + ((k4 & 3) * 16 + lr) * 4;
    f32x4 g0 = *(const f32x4*)(gsumG + fidx);
    f32x4 g1 = *(const f32x4*)(gsumG + C * C + fidx);
#pragma unroll
    for (int q = 0; q < 4; ++q) {
      float pw = psW[(size_t)(k4 * 4 + q) * (RANK * C)];
      a0 += pw * g0[q];
      a1 += pw * g1[q];
    }
  }
  red[0][kg][c32] = a0;
  red[1][kg][c32] = a1;
  __syncthreads();
  if (tid < 64) {
    int b = tid >> 5, cc = tid & 31;
    float s = 0.f;
#pragma unroll
    for (int g = 0; g < 8; ++g) s += red[b][g][cc];
    int cg = ch * 32 + cc;
    s += psi_b[r * C + cg] * gsumS[b * C + cg];
    s *= (1.0f / NB);
    int nt = cg >> 4, kt = r >> 5;
    int lane = ((r >> 3) & 3) * 16 + (cg & 15), j = r & 7;
    itf[(size_t)(((b * 8 + nt) * 2 + kt) * 64 + lane) * 8 + j] = f2b(s);
  }
}

// ---------------------------------------------------------------------------
// k_main: 32 rows/block, 256 threads (4 waves = 4 col-tiles), MFMA fused.
// A-fragments loaded directly from row-major f32 x (L3-warm), converted
// in-register; single barrier (phi exchange).
//   T1 phi = x*phi_w + phi_b ; T2 acc = x*W_w + W_b ; T3 acc += phi*integ
//   out = gelu_fast(acc)
// ---------------------------------------------------------------------------
__global__ __launch_bounds__(256, 2) void k_main(
    const float* __restrict__ x, const float* __restrict__ W_b,
    const float* __restrict__ phi_b, const unsigned short* __restrict__ wtf,
    const unsigned short* __restrict__ pwf, const unsigned short* __restrict__ itf,
    float* __restrict__ out) {
  __shared__ short phT[32 * 72];
  const int tid = threadIdx.x, l = tid & 63, wn = tid >> 6;
  const int row0 = blockIdx.x * 32;
  const int b = blockIdx.x >> 8;
  const int lr = l & 15, lq = l >> 4;
  bf16x8 wb[2][4], pw[4], itb[2][2];
  const bf16x8* WF = (const bf16x8*)wtf;
  const bf16x8* PF = (const bf16x8*)pwf;
  const bf16x8* IF = (const bf16x8*)itf;
#pragma unroll
  for (int j = 0; j < 2; ++j)
#pragma unroll
    for (int kt = 0; kt < 4; ++kt)
      wb[j][kt] = WF[((wn * 2 + j) * 4 + kt) * 64 + l];
#pragma unroll
  for (int kt = 0; kt < 4; ++kt) pw[kt] = PF[(wn * 4 + kt) * 64 + l];
#pragma unroll
  for (int j = 0; j < 2; ++j)
#pragma unroll
    for (int kt = 0; kt < 2; ++kt)
      itb[j][kt] = IF[((b * 8 + wn * 2 + j) * 2 + kt) * 64 + l];
  bf16x8 afr[2][4];
#pragma unroll
  for (int h = 0; h < 2; ++h) {
    const float* xr = x + (size_t)(row0 + h * 16 + lr) * C + lq * 8;
#pragma unroll
    for (int kt = 0; kt < 4; ++kt) {
      f32x4 v0 = *(const f32x4*)(xr + kt * 32);
      f32x4 v1 = *(const f32x4*)(xr + kt * 32 + 4);
      bf16x8 pv;
#pragma unroll
      for (int q = 0; q < 4; ++q) {
        pv[q] = (short)f2b(v0[q]);
        pv[q + 4] = (short)f2b(v1[q]);
      }
      afr[h][kt] = pv;
    }
  }
  float wb0 = W_b[wn * 32 + lr], wb1 = W_b[wn * 32 + 16 + lr];
  float pb0 = phi_b[wn * 16 + lr];
  f32x4 acc[2][2], pacc[2];
#pragma unroll
  for (int i = 0; i < 2; ++i) {
    acc[i][0] = (f32x4)(wb0);
    acc[i][1] = (f32x4)(wb1);
    pacc[i] = (f32x4)(pb0);
  }
#pragma unroll
  for (int kt = 0; kt < 4; ++kt) {
    pacc[0] = MFMA(afr[0][kt], pw[kt], pacc[0]);
    pacc[1] = MFMA(afr[1][kt], pw[kt], pacc[1]);
    acc[0][0] = MFMA(afr[0][kt], wb[0][kt], acc[0][0]);
    acc[0][1] = MFMA(afr[0][kt], wb[1][kt], acc[0][1]);
    acc[1][0] = MFMA(afr[1][kt], wb[0][kt], acc[1][0]);
    acc[1][1] = MFMA(afr[1][kt], wb[1][kt], acc[1][1]);
  }
#pragma unroll
  for (int i = 0; i < 2; ++i)
#pragma unroll
    for (int q = 0; q < 4; ++q) {
      int row = i * 16 + lq * 4 + q;
      phT[row * 72 + wn * 16 + lr] = (short)f2b(pacc[i][q]);
    }
  __syncthreads();
#pragma unroll
  for (int kt = 0; kt < 2; ++kt) {
    bf16x8 p0 = *(const bf16x8*)(&phT[lr * 72 + kt * 32 + lq * 8]);
    bf16x8 p1 = *(const bf16x8*)(&phT[(16 + lr) * 72 + kt * 32 + lq * 8]);
    acc[0][0] = MFMA(p0, itb[0][kt], acc[0][0]);
    acc[0][1] = MFMA(p0, itb[1][kt], acc[0][1]);
    acc[1][0] = MFMA(p1, itb[0][kt], acc[1][0]);
    acc[1][1] = MFMA(p1, itb[1][kt], acc[1][1]);
  }
#pragma unroll
  for (int i = 0; i < 2; ++i)
#pragma unroll
    for (int j = 0; j < 2; ++j)
#pragma unroll
      for (int q = 0; q < 4; ++q) {
        int row = row0 + i * 16 + lq * 4 + q;
        int col = wn * 32 + j * 16 + lr;
        out[(size_t)row * C + col] = gelu_fast(acc[i][j][q]);
      }
}

extern "C" void kernel_launch(void* const* d_in, const int* in_sizes, int n_in,
                              void* d_out, int out_size, void* d_ws, size_t ws_size,
                              hipStream_t stream) {
  const float* x     = (const float*)d_in[0];
  const float* W_w   = (const float*)d_in[1];
  const float* W_b   = (const float*)d_in[2];
  const float* phi_w = (const float*)d_in[3];
  const float* phi_b = (const float*)d_in[4];
  const float* psi_w = (const float*)d_in[5];
  const float* psi_b = (const float*)d_in[6];
  float* out = (float*)d_out;

  // ws: partG[256*16384 bf16] | partS[256*128 f32] | gsumG[2*16384 f32]
  //     | gsumS[256 f32] | wtf[16384 bf16] | pwf[8192 bf16] | itf[16384 bf16]
  unsigned short* partG = (unsigned short*)d_ws;
  float* partS = (float*)(partG + (size_t)BATCH * NCHUNK * C * C);
  float* gsumG = partS + (size_t)BATCH * NCHUNK * C;
  float* gsumS = gsumG + BATCH * C * C;
  unsigned short* wtf = (unsigned short*)(gsumS + BATCH * C);
  unsigned short* pwf = wtf + 16384;
  unsigned short* itf = pwf + 8192;

  k_gram<<<BATCH * NCHUNK + 12, 512, 0, stream>>>(x, partG, partS, wtf, pwf,
                                                  W_w, phi_w);
  k_reduce<<<258, 256, 0, stream>>>(partG, partS, gsumG, gsumS);
  k_integral<<<dim3(RANK, 4), 256, 0, stream>>>(psi_w, psi_b, gsumG, gsumS,
                                                itf);
  k_main<<<(BATCH * NB) / 32, 256, 0, stream>>>(x, W_b, phi_b, wtf, pwf, itf,
                                                out);
}